// Round 6
// baseline (299.870 us; speedup 1.0000x reference)
//
#include <hip/hip_runtime.h>
#include <cstdint>

#define LRELU_SLOPE 0.2f
#define ELL_K 48

typedef short bf16x8_t __attribute__((ext_vector_type(8)));
typedef float f32x4_t  __attribute__((ext_vector_type(4)));

__device__ __forceinline__ float bf2f(unsigned int u) { return __uint_as_float(u << 16); }
__device__ __forceinline__ unsigned short f2bf(float f) {
    unsigned int x = __float_as_uint(f);
    return (unsigned short)((x + 0x7fffu + ((x >> 16) & 1u)) >> 16);
}

// ---------------- fused prep: dtype probe, W1/W2 transpose->bf16, small canon->f32,
// zero deg. flags[0]!=0 => edges int32; flags[1]!=0 => floats bf16.
struct PrepDesc { const void* ssrc[6]; float* sdst[6]; int slen[6]; };
__global__ __launch_bounds__(256) void prep_k(const unsigned short* __restrict__ xh,
                                              const int* __restrict__ ei32,
                                              const void* __restrict__ w1raw,
                                              const void* __restrict__ w2raw,
                                              unsigned short* __restrict__ Wt1,
                                              unsigned short* __restrict__ Wt2,
                                              PrepDesc d, int* __restrict__ flags,
                                              int* __restrict__ deg, int N) {
    __shared__ int s_ei, s_cnt;
    if (threadIdx.x == 0) { s_ei = 0; s_cnt = 0; }
    __syncthreads();
    const int t = threadIdx.x;
    int e_or = 0;
#pragma unroll
    for (int j = 0; j < 4; j++) if (ei32[2 * (t * 4 + j) + 1] != 0) e_or = 1;
    if (e_or) atomicOr(&s_ei, 1);
    int c = 0;
#pragma unroll
    for (int j = 0; j < 8; j++) {
        unsigned short h = xh[t * 8 + j];
        int e = (h >> 7) & 0xFF;
        if (e >= 117 && e < 134) c++;
    }
    atomicAdd(&s_cnt, c);
    __syncthreads();
    const int isb = (s_cnt >= 1600) ? 1 : 0;
    if (blockIdx.x == 0 && t == 0) { flags[0] = s_ei; flags[1] = isb; }
    const int gstride = gridDim.x * blockDim.x;
    const int gid = blockIdx.x * blockDim.x + t;
    for (int i = gid; i < 128 * 256; i += gstride) {       // W1T
        int k = i >> 8, n = i & 255;
        unsigned short b = isb ? ((const unsigned short*)w1raw)[i] : f2bf(((const float*)w1raw)[i]);
        Wt1[n * 128 + k] = b;
    }
    for (int i = gid; i < 256 * 64; i += gstride) {        // W2T
        int k = i >> 6, n = i & 63;
        unsigned short b = isb ? ((const unsigned short*)w2raw)[i] : f2bf(((const float*)w2raw)[i]);
        Wt2[n * 256 + k] = b;
    }
#pragma unroll
    for (int s = 0; s < 6; s++)
        for (int i = gid; i < d.slen[s]; i += gstride) {
            float v = isb ? bf2f((unsigned int)((const unsigned short*)d.ssrc[s])[i])
                          : ((const float*)d.ssrc[s])[i];
            d.sdst[s][i] = v;
        }
    for (int i = gid; i < N; i += gstride) deg[i] = 0;
}

// ---------------- GEMM1 via MFMA + fused alpha1 (clean R14 form)
__global__ __launch_bounds__(256) void gemm1_k(const void* __restrict__ xraw,
                                               const unsigned short* __restrict__ Wt,
                                               const float* __restrict__ asw_,
                                               const float* __restrict__ adw_,
                                               unsigned short* __restrict__ h,
                                               float* __restrict__ as_, float* __restrict__ ad_,
                                               int M, const int* __restrict__ flags) {
    __shared__ unsigned short xs[64 * 136];
    const int tid = threadIdx.x;
    const long row0 = (long)blockIdx.x * 64;
    if (flags[1] != 0) {
        const uint4* xv = (const uint4*)xraw;
        const long base = row0 * 16;
        const long lim = (long)M * 16 - base;
#pragma unroll
        for (int i = 0; i < 4; i++) {
            int idx = tid + i * 256;
            uint4 v;
            if (idx < lim) v = xv[base + idx];
            else { v.x = v.y = v.z = v.w = 0u; }
            int r = idx >> 4, c8 = idx & 15;
            *(uint4*)&xs[r * 136 + c8 * 8] = v;
        }
    } else {
        const float4* xv = (const float4*)xraw;
        const long base = row0 * 32;
        const long lim = (long)M * 32 - base;
#pragma unroll
        for (int i = 0; i < 8; i++) {
            int idx = tid + i * 256;
            float4 v;
            if (idx < lim) v = xv[base + idx];
            else { v.x = v.y = v.z = v.w = 0.f; }
            int r = idx >> 5, c4 = idx & 31;
            ushort4 o;
            o.x = f2bf(v.x); o.y = f2bf(v.y); o.z = f2bf(v.z); o.w = f2bf(v.w);
            *(ushort4*)&xs[r * 136 + c4 * 4] = o;
        }
    }
    __syncthreads();
    const int wv = tid >> 6;
    const int lane = tid & 63;
    const int l16 = lane & 15, quad = lane >> 4;
    bf16x8_t af[4];
#pragma unroll
    for (int ks = 0; ks < 4; ks++)
        af[ks] = *(const bf16x8_t*)&xs[(wv * 16 + l16) * 136 + ks * 32 + quad * 8];
    float psA[4] = {0.f, 0.f, 0.f, 0.f}, pdA[4] = {0.f, 0.f, 0.f, 0.f};
#pragma unroll
    for (int t = 0; t < 16; t++) {
        f32x4_t acc = {0.f, 0.f, 0.f, 0.f};
#pragma unroll
        for (int ks = 0; ks < 4; ks++) {
            bf16x8_t bf = *(const bf16x8_t*)(Wt + (size_t)(t * 16 + l16) * 128 + ks * 32 + quad * 8);
            acc = __builtin_amdgcn_mfma_f32_16x16x32_bf16(af[ks], bf, acc, 0, 0, 0);
        }
        const float aswv = asw_[t * 16 + l16];
        const float adwv = adw_[t * 16 + l16];
#pragma unroll
        for (int r = 0; r < 4; r++) {
            long grow = row0 + wv * 16 + quad * 4 + r;
            if (grow < M) h[grow * 256 + t * 16 + l16] = f2bf(acc[r]);
            psA[r] = fmaf(acc[r], aswv, psA[r]);
            pdA[r] = fmaf(acc[r], adwv, pdA[r]);
        }
        if ((t & 3) == 3) {
            const int hd = t >> 2;
#pragma unroll
            for (int r = 0; r < 4; r++) {
                float ps = psA[r], pd = pdA[r];
#pragma unroll
                for (int o = 8; o > 0; o >>= 1) {
                    ps += __shfl_down(ps, o, 16);
                    pd += __shfl_down(pd, o, 16);
                }
                long grow = row0 + wv * 16 + quad * 4 + r;
                if (l16 == 0 && grow < M) { as_[grow * 4 + hd] = ps; ad_[grow * 4 + hd] = pd; }
                psA[r] = 0.f; pdA[r] = 0.f;
            }
        }
    }
}

// ---------------- ELL build, slim: ONE atomic pass = rank + src scatter ONLY.
// (alpha/softmax numerators moved into agg1 — kills ell's random float4 gathers
// and the 8B partial-line RMW scatter of ell_pw.)
__global__ void ell_k(const int* __restrict__ ei, int E, int N,
                      const int* __restrict__ flags, int* __restrict__ deg,
                      int* __restrict__ ell_src) {
    int i = blockIdx.x * blockDim.x + threadIdx.x;
    int T = E + N;
    if (i >= T) return;
    int is64 = (flags[0] == 0);
    int s, d;
    if (i < E) {
        s = is64 ? ei[2 * (long)i] : ei[i];
        long k = (long)E + i;
        d = is64 ? ei[2 * k] : ei[k];
    } else { s = d = i - E; }
    if ((unsigned)d >= (unsigned)N) return;
    if ((unsigned)s >= (unsigned)N) s = 0;
    int r = atomicAdd(&deg[d], 1);
    if (r >= ELL_K) return;                    // cosmically unlikely; agg clamps too
    ell_src[(long)d * ELL_K + r] = s;
}

// ---------------- GEMM2 via MFMA + fused alpha2 (unchanged)
__global__ __launch_bounds__(256) void gemm2_k(const unsigned short* __restrict__ x,
                                               const unsigned short* __restrict__ Wt,
                                               const float* __restrict__ asw_,
                                               const float* __restrict__ adw_,
                                               unsigned short* __restrict__ h,
                                               float* __restrict__ as_, float* __restrict__ ad_,
                                               int M) {
    __shared__ unsigned short xs[64 * 264];
    const int tid = threadIdx.x;
    const long row0 = (long)blockIdx.x * 64;
    const uint4* xv = (const uint4*)x;
    const long base = row0 * 32;
    const long lim = (long)M * 32 - base;
#pragma unroll
    for (int i = 0; i < 8; i++) {
        int idx = tid + i * 256;
        uint4 v;
        if (idx < lim) v = xv[base + idx];
        else { v.x = v.y = v.z = v.w = 0u; }
        int r = idx >> 5, c8 = idx & 31;
        *(uint4*)&xs[r * 264 + c8 * 8] = v;
    }
    __syncthreads();
    const int wv = tid >> 6;
    const int lane = tid & 63;
    const int l16 = lane & 15, quad = lane >> 4;
    bf16x8_t af[8];
#pragma unroll
    for (int ks = 0; ks < 8; ks++)
        af[ks] = *(const bf16x8_t*)&xs[(wv * 16 + l16) * 264 + ks * 32 + quad * 8];
    float psA[4] = {0.f, 0.f, 0.f, 0.f}, pdA[4] = {0.f, 0.f, 0.f, 0.f};
#pragma unroll
    for (int t = 0; t < 4; t++) {
        f32x4_t acc = {0.f, 0.f, 0.f, 0.f};
#pragma unroll
        for (int ks = 0; ks < 8; ks++) {
            bf16x8_t bf = *(const bf16x8_t*)(Wt + (size_t)(t * 16 + l16) * 256 + ks * 32 + quad * 8);
            acc = __builtin_amdgcn_mfma_f32_16x16x32_bf16(af[ks], bf, acc, 0, 0, 0);
        }
        const float aswv = asw_[t * 16 + l16];
        const float adwv = adw_[t * 16 + l16];
#pragma unroll
        for (int r = 0; r < 4; r++) {
            long grow = row0 + wv * 16 + quad * 4 + r;
            if (grow < M) h[grow * 64 + t * 16 + l16] = f2bf(acc[r]);
            psA[r] = fmaf(acc[r], aswv, psA[r]);
            pdA[r] = fmaf(acc[r], adwv, pdA[r]);
        }
    }
#pragma unroll
    for (int r = 0; r < 4; r++) {
        float ps = psA[r], pd = pdA[r];
#pragma unroll
        for (int o = 8; o > 0; o >>= 1) { ps += __shfl_down(ps, o, 16); pd += __shfl_down(pd, o, 16); }
        long grow = row0 + wv * 16 + quad * 4 + r;
        if (l16 == 0 && grow < M) { as_[grow] = ps; ad_[grow] = pd; }
    }
}

// X-macro: 20 pipeline slots
#define B20(M) M(0) M(1) M(2) M(3) M(4) M(5) M(6) M(7) M(8) M(9) \
               M(10) M(11) M(12) M(13) M(14) M(15) M(16) M(17) M(18) M(19)

// ---------------- layer-1 aggregate: one node per 32-lane group, uint4/lane.
// Lane-parallel ell_src preload + intra-32 shfl broadcast; attention weight
// computed IN-KERNEL from as1 gather (L2-resident, 800KB) + hoisted ad1 —
// ell_pw is gone. 20-slot issue window + guarded tail.
__global__ __launch_bounds__(256) void agg1_k(const uint4* __restrict__ hfeat,
                                              const int* __restrict__ deg,
                                              const int* __restrict__ ell_src,
                                              const float* __restrict__ as1,
                                              const float* __restrict__ ad1,
                                              const float* __restrict__ bias,
                                              unsigned short* __restrict__ outb, int N) {
    const int tid = threadIdx.x;
    const int g = tid >> 5;            // group 0..7 (one node each)
    const int c = tid & 31;            // uint4 column: bf16 channels [8c, 8c+8)
    const long node = (long)blockIdx.x * 8 + g;
    if (node >= N) return;
    const int hh = c >> 3;             // head 0..3 (channel block 64*hh)
    const long beg = node * ELL_K;
    // independent preloads: deg + 48 edge ids + this head's dst coefficient
    const int dv = deg[node];
    const int siA = ell_src[beg + c];                 // edges 0..31 (lane c)
    const int siB = ell_src[beg + 32 + (c & 15)];     // edges 32..47
    const float adv_ = ad1[node * 4 + hh];
    const int cnt = dv < ELL_K ? dv : ELL_K;
    float a0 = 0.f, a1 = 0.f, a2 = 0.f, a3 = 0.f;
    float a4 = 0.f, a5 = 0.f, a6 = 0.f, a7 = 0.f, s = 0.f;
#define EDGE8(v, p) { \
        a0 = fmaf(p, __uint_as_float((v).x << 16), a0); \
        a1 = fmaf(p, __uint_as_float((v).x & 0xffff0000u), a1); \
        a2 = fmaf(p, __uint_as_float((v).y << 16), a2); \
        a3 = fmaf(p, __uint_as_float((v).y & 0xffff0000u), a3); \
        a4 = fmaf(p, __uint_as_float((v).z << 16), a4); \
        a5 = fmaf(p, __uint_as_float((v).z & 0xffff0000u), a5); \
        a6 = fmaf(p, __uint_as_float((v).w << 16), a6); \
        a7 = fmaf(p, __uint_as_float((v).w & 0xffff0000u), a7); \
        s += p; }
#define DECL1(k) uint4 vv##k; float av##k;
#define ISSUE1(k) if (j + k < cnt) { \
        const int e = j + k; \
        const int sv = __shfl((e < 32) ? siA : siB, e & 31, 32); \
        vv##k = hfeat[(long)sv * 32 + c]; \
        av##k = as1[sv * 4 + hh]; }
#define CONS1(k) if (j + k < cnt) { \
        float t = av##k + adv_; t = t > 0.f ? t : LRELU_SLOPE * t; \
        const float p = __expf(t); \
        EDGE8(vv##k, p) }
    {   // main pass: edges 0..19 all in flight before first consume
        const int j = 0;
        B20(DECL1)
        B20(ISSUE1)
        B20(CONS1)
    }
    if (cnt > 20) {  // tail pass: edges 20..47 (~18% of nodes)
        const int j = 20;
        B20(DECL1)
        B20(ISSUE1)
        B20(CONS1)
        if (cnt > 40) {
            const int j2 = 40;
#define ISSUE1b(k) if (j2 + k < cnt) { \
            const int e = j2 + k; \
            const int sv = __shfl((e < 32) ? siA : siB, e & 31, 32); \
            vv##k = hfeat[(long)sv * 32 + c]; \
            av##k = as1[sv * 4 + hh]; }
#define CONS1b(k) if (j2 + k < cnt) { \
            float t = av##k + adv_; t = t > 0.f ? t : LRELU_SLOPE * t; \
            const float p = __expf(t); \
            EDGE8(vv##k, p) }
            ISSUE1b(0) ISSUE1b(1) ISSUE1b(2) ISSUE1b(3)
            ISSUE1b(4) ISSUE1b(5) ISSUE1b(6) ISSUE1b(7)
            CONS1b(0) CONS1b(1) CONS1b(2) CONS1b(3)
            CONS1b(4) CONS1b(5) CONS1b(6) CONS1b(7)
#undef ISSUE1b
#undef CONS1b
        }
    }
#undef DECL1
#undef ISSUE1
#undef CONS1
#undef EDGE8
    const float4 b0 = ((const float4*)bias)[2 * c];
    const float4 b1 = ((const float4*)bias)[2 * c + 1];
    const float inv = 1.f / s;
    uint4 o;
    o.x = (unsigned)f2bf(fmaxf(fmaf(a0, inv, b0.x), 0.f)) |
          ((unsigned)f2bf(fmaxf(fmaf(a1, inv, b0.y), 0.f)) << 16);
    o.y = (unsigned)f2bf(fmaxf(fmaf(a2, inv, b0.z), 0.f)) |
          ((unsigned)f2bf(fmaxf(fmaf(a3, inv, b0.w), 0.f)) << 16);
    o.z = (unsigned)f2bf(fmaxf(fmaf(a4, inv, b1.x), 0.f)) |
          ((unsigned)f2bf(fmaxf(fmaf(a5, inv, b1.y), 0.f)) << 16);
    o.w = (unsigned)f2bf(fmaxf(fmaf(a6, inv, b1.z), 0.f)) |
          ((unsigned)f2bf(fmaxf(fmaf(a7, inv, b1.w), 0.f)) << 16);
    ((uint4*)outb)[node * 32 + c] = o;
}

// ---------------- layer-2 aggregate (H=1): one node per 16-lane group, uint2/lane.
// Lane-parallel si/alpha preload (clamped before indexing as_), intra-16 shfl
// broadcast, 20-slot issue window + guarded tail. (unchanged from R5)
__global__ __launch_bounds__(256) void agg2_k(const unsigned short* __restrict__ hfeat,
                                              const float* __restrict__ as_,
                                              const float* __restrict__ ad_,
                                              const int* __restrict__ deg,
                                              const int* __restrict__ ell_src,
                                              const float* __restrict__ bias,
                                              unsigned short* __restrict__ outb,
                                              float* __restrict__ outf,
                                              const int* __restrict__ flags, int N) {
    const int tid = threadIdx.x;
    const int g = tid >> 4;            // group 0..15 (one node each)
    const int c = tid & 15;            // uint2 column: bf16 channels [4c, 4c+4)
    const long node = (long)blockIdx.x * 16 + g;
    if (node >= N) return;
    const long beg = node * ELL_K;
    const int dv = deg[node];
    const int rA = ell_src[beg + c];           // edges 0..15
    const int rB = ell_src[beg + 16 + c];      // edges 16..31
    const int rC = ell_src[beg + 32 + c];      // edges 32..47
    const float adn = ad_[node];
    const int cnt = dv < ELL_K ? dv : ELL_K;
    // clamp garbage slots (uninitialized ell rows) before indexing as_
    const int sA = (c      < cnt) ? rA : 0;
    const int sB = (c + 16 < cnt) ? rB : 0;
    const int sC = (c + 32 < cnt) ? rC : 0;
    const float avA = as_[sA];
    const float avB = as_[sB];
    const float avC = as_[sC];
    const uint2* hv = (const uint2*)hfeat;
    float sm = 0.f, a0 = 0.f, a1 = 0.f, a2 = 0.f, a3 = 0.f;
#define EDGE4(v, p) { \
        a0 = fmaf(p, __uint_as_float((v).x << 16), a0); \
        a1 = fmaf(p, __uint_as_float((v).x & 0xffff0000u), a1); \
        a2 = fmaf(p, __uint_as_float((v).y << 16), a2); \
        a3 = fmaf(p, __uint_as_float((v).y & 0xffff0000u), a3); \
        sm += p; }
#define DECL2(k) uint2 vv##k;
#define ISSUE2(k) if (j + k < cnt) { \
        const int e = j + k; \
        const int sv = __shfl((e < 16) ? sA : ((e < 32) ? sB : sC), e & 15, 16); \
        vv##k = hv[(long)sv * 16 + c]; }
#define CONS2(k) if (j + k < cnt) { \
        const int e = j + k; \
        const float av = __shfl((e < 16) ? avA : ((e < 32) ? avB : avC), e & 15, 16); \
        float t = av + adn; t = t > 0.f ? t : LRELU_SLOPE * t; \
        const float p = __expf(t); \
        EDGE4(vv##k, p) }
    {   // main pass: edges 0..19
        const int j = 0;
        B20(DECL2)
        B20(ISSUE2)
        B20(CONS2)
    }
    if (cnt > 20) {  // tail: edges 20..47
        const int j = 20;
        B20(DECL2)
        B20(ISSUE2)
        B20(CONS2)
        if (cnt > 40) {
            const int j2 = 40;
#define ISSUE2b(k) if (j2 + k < cnt) { \
            const int e = j2 + k; \
            const int sv = __shfl((e < 16) ? sA : ((e < 32) ? sB : sC), e & 15, 16); \
            vv##k = hv[(long)sv * 16 + c]; }
#define CONS2b(k) if (j2 + k < cnt) { \
            const int e = j2 + k; \
            const float av = __shfl((e < 16) ? avA : ((e < 32) ? avB : avC), e & 15, 16); \
            float t = av + adn; t = t > 0.f ? t : LRELU_SLOPE * t; \
            const float p = __expf(t); \
            EDGE4(vv##k, p) }
            ISSUE2b(0) ISSUE2b(1) ISSUE2b(2) ISSUE2b(3)
            ISSUE2b(4) ISSUE2b(5) ISSUE2b(6) ISSUE2b(7)
            CONS2b(0) CONS2b(1) CONS2b(2) CONS2b(3)
            CONS2b(4) CONS2b(5) CONS2b(6) CONS2b(7)
#undef ISSUE2b
#undef CONS2b
        }
    }
#undef DECL2
#undef ISSUE2
#undef CONS2
#undef EDGE4
    const float inv = 1.f / sm;
    const float4 bi = ((const float4*)bias)[c];
    const float v0 = fmaf(a0, inv, bi.x);
    const float v1 = fmaf(a1, inv, bi.y);
    const float v2 = fmaf(a2, inv, bi.z);
    const float v3 = fmaf(a3, inv, bi.w);
    if (flags[1] != 0) {
        uint2 o;
        o.x = (unsigned)f2bf(v0) | ((unsigned)f2bf(v1) << 16);
        o.y = (unsigned)f2bf(v2) | ((unsigned)f2bf(v3) << 16);
        ((uint2*)outb)[node * 16 + c] = o;
    } else {
        float4 o; o.x = v0; o.y = v1; o.z = v2; o.w = v3;
        ((float4*)outf)[node * 16 + c] = o;
    }
}

static inline size_t alignup(size_t v, size_t a) { return (v + a - 1) & ~(a - 1); }

extern "C" void kernel_launch(void* const* d_in, const int* in_sizes, int n_in,
                              void* d_out, int out_size, void* d_ws, size_t ws_size,
                              hipStream_t stream) {
    const void* x  = d_in[0];
    const int*  ei = (const int*)d_in[1];

    const int N = in_sizes[0] / 128;   // 50000
    const int E = in_sizes[1] / 2;     // 800000
    const int T = E + N;

    size_t off = 0;
    char* w = (char*)d_ws;
    auto take = [&](size_t bytes) { void* p = w + off; off = alignup(off + bytes, 256); return p; };

    int*   flags = (int*)take(256);
    unsigned short* Wt1 = (unsigned short*)take((size_t)256 * 128 * 2);
    unsigned short* Wt2 = (unsigned short*)take((size_t)64 * 256 * 2);
    float* as1w = (float*)take(256 * 4);
    float* ad1w = (float*)take(256 * 4);
    float* b1f  = (float*)take(256 * 4);
    float* as2w = (float*)take(64 * 4);
    float* ad2w = (float*)take(64 * 4);
    float* b2f  = (float*)take(64 * 4);
    unsigned short* h1b   = (unsigned short*)take((size_t)N * 256 * 2);  // reused as h2b
    unsigned short* act1b = (unsigned short*)take((size_t)N * 256 * 2);
    float* as1 = (float*)take((size_t)N * 4 * 4);
    float* ad1 = (float*)take((size_t)N * 4 * 4);
    float* as2 = (float*)take((size_t)N * 4);
    float* ad2 = (float*)take((size_t)N * 4);
    int* deg   = (int*)take((size_t)N * 4);
    int* ell_src = (int*)take((size_t)N * ELL_K * 4);
    unsigned short* h2b = h1b;  // h1b dead after agg1

    PrepDesc pd;
    pd.ssrc[0] = d_in[3]; pd.sdst[0] = as1w; pd.slen[0] = 256;
    pd.ssrc[1] = d_in[4]; pd.sdst[1] = ad1w; pd.slen[1] = 256;
    pd.ssrc[2] = d_in[5]; pd.sdst[2] = b1f;  pd.slen[2] = 256;
    pd.ssrc[3] = d_in[7]; pd.sdst[3] = as2w; pd.slen[3] = 64;
    pd.ssrc[4] = d_in[8]; pd.sdst[4] = ad2w; pd.slen[4] = 64;
    pd.ssrc[5] = d_in[9]; pd.sdst[5] = b2f;  pd.slen[5] = 64;
    prep_k<<<64, 256, 0, stream>>>((const unsigned short*)x, ei, d_in[2], d_in[6],
                                   Wt1, Wt2, pd, flags, deg, N);

    gemm1_k<<<(N + 63) / 64, 256, 0, stream>>>(x, Wt1, as1w, ad1w, h1b, as1, ad1, N, flags);
    ell_k<<<(T + 255) / 256, 256, 0, stream>>>(ei, E, N, flags, deg, ell_src);
    agg1_k<<<(N + 7) / 8, 256, 0, stream>>>((const uint4*)h1b, deg, ell_src, as1, ad1, b1f, act1b, N);
    gemm2_k<<<(N + 63) / 64, 256, 0, stream>>>(act1b, Wt2, as2w, ad2w, h2b, as2, ad2, N);
    agg2_k<<<(N + 15) / 16, 256, 0, stream>>>(h2b, as2, ad2, deg, ell_src, b2f,
                                              (unsigned short*)d_out, (float*)d_out, flags, N);
}

// Round 7
// 273.914 us; speedup vs baseline: 1.0948x; 1.0948x over previous
//
#include <hip/hip_runtime.h>
#include <cstdint>

#define LRELU_SLOPE 0.2f
#define ELL_K 48

typedef short bf16x8_t __attribute__((ext_vector_type(8)));
typedef float f32x4_t  __attribute__((ext_vector_type(4)));

__device__ __forceinline__ float bf2f(unsigned int u) { return __uint_as_float(u << 16); }
__device__ __forceinline__ unsigned short f2bf(float f) {
    unsigned int x = __float_as_uint(f);
    return (unsigned short)((x + 0x7fffu + ((x >> 16) & 1u)) >> 16);
}
__device__ __forceinline__ unsigned short f2h(float f) {
    union { unsigned short u; _Float16 h; } cv; cv.h = (_Float16)f; return cv.u;
}
__device__ __forceinline__ float h2f(unsigned short u) {
    union { unsigned short u; _Float16 h; } cv; cv.u = u; return (float)cv.h;
}

// ---------------- fused prep: dtype probe, W1/W2 transpose->bf16, small canon->f32,
// zero deg. flags[0]!=0 => edges int32; flags[1]!=0 => floats bf16.
struct PrepDesc { const void* ssrc[6]; float* sdst[6]; int slen[6]; };
__global__ __launch_bounds__(256) void prep_k(const unsigned short* __restrict__ xh,
                                              const int* __restrict__ ei32,
                                              const void* __restrict__ w1raw,
                                              const void* __restrict__ w2raw,
                                              unsigned short* __restrict__ Wt1,
                                              unsigned short* __restrict__ Wt2,
                                              PrepDesc d, int* __restrict__ flags,
                                              int* __restrict__ deg, int N) {
    __shared__ int s_ei, s_cnt;
    if (threadIdx.x == 0) { s_ei = 0; s_cnt = 0; }
    __syncthreads();
    const int t = threadIdx.x;
    int e_or = 0;
#pragma unroll
    for (int j = 0; j < 4; j++) if (ei32[2 * (t * 4 + j) + 1] != 0) e_or = 1;
    if (e_or) atomicOr(&s_ei, 1);
    int c = 0;
#pragma unroll
    for (int j = 0; j < 8; j++) {
        unsigned short h = xh[t * 8 + j];
        int e = (h >> 7) & 0xFF;
        if (e >= 117 && e < 134) c++;
    }
    atomicAdd(&s_cnt, c);
    __syncthreads();
    const int isb = (s_cnt >= 1600) ? 1 : 0;
    if (blockIdx.x == 0 && t == 0) { flags[0] = s_ei; flags[1] = isb; }
    const int gstride = gridDim.x * blockDim.x;
    const int gid = blockIdx.x * blockDim.x + t;
    for (int i = gid; i < 128 * 256; i += gstride) {       // W1T
        int k = i >> 8, n = i & 255;
        unsigned short b = isb ? ((const unsigned short*)w1raw)[i] : f2bf(((const float*)w1raw)[i]);
        Wt1[n * 128 + k] = b;
    }
    for (int i = gid; i < 256 * 64; i += gstride) {        // W2T
        int k = i >> 6, n = i & 63;
        unsigned short b = isb ? ((const unsigned short*)w2raw)[i] : f2bf(((const float*)w2raw)[i]);
        Wt2[n * 256 + k] = b;
    }
#pragma unroll
    for (int s = 0; s < 6; s++)
        for (int i = gid; i < d.slen[s]; i += gstride) {
            float v = isb ? bf2f((unsigned int)((const unsigned short*)d.ssrc[s])[i])
                          : ((const float*)d.ssrc[s])[i];
            d.sdst[s][i] = v;
        }
    for (int i = gid; i < N; i += gstride) deg[i] = 0;
}

// ---------------- GEMM1 via MFMA + fused alpha1 (clean R14 form)
__global__ __launch_bounds__(256) void gemm1_k(const void* __restrict__ xraw,
                                               const unsigned short* __restrict__ Wt,
                                               const float* __restrict__ asw_,
                                               const float* __restrict__ adw_,
                                               unsigned short* __restrict__ h,
                                               float* __restrict__ as_, float* __restrict__ ad_,
                                               int M, const int* __restrict__ flags) {
    __shared__ unsigned short xs[64 * 136];
    const int tid = threadIdx.x;
    const long row0 = (long)blockIdx.x * 64;
    if (flags[1] != 0) {
        const uint4* xv = (const uint4*)xraw;
        const long base = row0 * 16;
        const long lim = (long)M * 16 - base;
#pragma unroll
        for (int i = 0; i < 4; i++) {
            int idx = tid + i * 256;
            uint4 v;
            if (idx < lim) v = xv[base + idx];
            else { v.x = v.y = v.z = v.w = 0u; }
            int r = idx >> 4, c8 = idx & 15;
            *(uint4*)&xs[r * 136 + c8 * 8] = v;
        }
    } else {
        const float4* xv = (const float4*)xraw;
        const long base = row0 * 32;
        const long lim = (long)M * 32 - base;
#pragma unroll
        for (int i = 0; i < 8; i++) {
            int idx = tid + i * 256;
            float4 v;
            if (idx < lim) v = xv[base + idx];
            else { v.x = v.y = v.z = v.w = 0.f; }
            int r = idx >> 5, c4 = idx & 31;
            ushort4 o;
            o.x = f2bf(v.x); o.y = f2bf(v.y); o.z = f2bf(v.z); o.w = f2bf(v.w);
            *(ushort4*)&xs[r * 136 + c4 * 4] = o;
        }
    }
    __syncthreads();
    const int wv = tid >> 6;
    const int lane = tid & 63;
    const int l16 = lane & 15, quad = lane >> 4;
    bf16x8_t af[4];
#pragma unroll
    for (int ks = 0; ks < 4; ks++)
        af[ks] = *(const bf16x8_t*)&xs[(wv * 16 + l16) * 136 + ks * 32 + quad * 8];
    float psA[4] = {0.f, 0.f, 0.f, 0.f}, pdA[4] = {0.f, 0.f, 0.f, 0.f};
#pragma unroll
    for (int t = 0; t < 16; t++) {
        f32x4_t acc = {0.f, 0.f, 0.f, 0.f};
#pragma unroll
        for (int ks = 0; ks < 4; ks++) {
            bf16x8_t bf = *(const bf16x8_t*)(Wt + (size_t)(t * 16 + l16) * 128 + ks * 32 + quad * 8);
            acc = __builtin_amdgcn_mfma_f32_16x16x32_bf16(af[ks], bf, acc, 0, 0, 0);
        }
        const float aswv = asw_[t * 16 + l16];
        const float adwv = adw_[t * 16 + l16];
#pragma unroll
        for (int r = 0; r < 4; r++) {
            long grow = row0 + wv * 16 + quad * 4 + r;
            if (grow < M) h[grow * 256 + t * 16 + l16] = f2bf(acc[r]);
            psA[r] = fmaf(acc[r], aswv, psA[r]);
            pdA[r] = fmaf(acc[r], adwv, pdA[r]);
        }
        if ((t & 3) == 3) {
            const int hd = t >> 2;
#pragma unroll
            for (int r = 0; r < 4; r++) {
                float ps = psA[r], pd = pdA[r];
#pragma unroll
                for (int o = 8; o > 0; o >>= 1) {
                    ps += __shfl_down(ps, o, 16);
                    pd += __shfl_down(pd, o, 16);
                }
                long grow = row0 + wv * 16 + quad * 4 + r;
                if (l16 == 0 && grow < M) { as_[grow * 4 + hd] = ps; ad_[grow * 4 + hd] = pd; }
                psA[r] = 0.f; pdA[r] = 0.f;
            }
        }
    }
}

// ---------------- ELL build (R5 form): ONE atomic pass = rank + src scatter +
// softmax numerators (f16x4 packed).
__global__ void ell_k(const int* __restrict__ ei, int E, int N,
                      const int* __restrict__ flags, int* __restrict__ deg,
                      int* __restrict__ ell_src, uint2* __restrict__ ell_pw,
                      const float* __restrict__ as1, const float* __restrict__ ad1) {
    int i = blockIdx.x * blockDim.x + threadIdx.x;
    int T = E + N;
    if (i >= T) return;
    int is64 = (flags[0] == 0);
    int s, d;
    if (i < E) {
        s = is64 ? ei[2 * (long)i] : ei[i];
        long k = (long)E + i;
        d = is64 ? ei[2 * k] : ei[k];
    } else { s = d = i - E; }
    if ((unsigned)d >= (unsigned)N) return;
    if ((unsigned)s >= (unsigned)N) s = 0;
    int r = atomicAdd(&deg[d], 1);
    if (r >= ELL_K) return;                    // cosmically unlikely; agg clamps too
    long slot = (long)d * ELL_K + r;
    ell_src[slot] = s;
    float4 a = ((const float4*)as1)[s];
    float4 b = ((const float4*)ad1)[d];
    float e0 = a.x + b.x, e1 = a.y + b.y, e2 = a.z + b.z, e3 = a.w + b.w;
    e0 = e0 > 0.f ? e0 : LRELU_SLOPE * e0;
    e1 = e1 > 0.f ? e1 : LRELU_SLOPE * e1;
    e2 = e2 > 0.f ? e2 : LRELU_SLOPE * e2;
    e3 = e3 > 0.f ? e3 : LRELU_SLOPE * e3;
    uint2 p;
    p.x = (unsigned)f2h(__expf(e0)) | ((unsigned)f2h(__expf(e1)) << 16);
    p.y = (unsigned)f2h(__expf(e2)) | ((unsigned)f2h(__expf(e3)) << 16);
    ell_pw[slot] = p;
}

// X-macro: 20 pipeline slots
#define B20(M) M(0) M(1) M(2) M(3) M(4) M(5) M(6) M(7) M(8) M(9) \
               M(10) M(11) M(12) M(13) M(14) M(15) M(16) M(17) M(18) M(19)

// ---------------- FUSED layer-1 aggregate + GEMM2: Phase A is R5's agg1_k
// (one node per 32-lane group, 20-slot issue window, ell_pw weights), but the
// 8x256 act1 tile goes to LDS (16x264, rows 8..15 zeroed) instead of global.
// Phase B (wave 0 after one barrier) is gemm2_k's MFMA loop with M=16 (8 real
// rows): writes h2 (64 cols) + fused as2/ad2. Kills act1b's 25.6MB write +
// 25.6MB read + one kernel launch.
__global__ __launch_bounds__(256) void agg1g2_k(const uint4* __restrict__ hfeat,
                                                const int* __restrict__ deg,
                                                const int* __restrict__ ell_src,
                                                const uint2* __restrict__ ell_pw,
                                                const float* __restrict__ bias,
                                                const unsigned short* __restrict__ Wt2,
                                                const float* __restrict__ asw2,
                                                const float* __restrict__ adw2,
                                                unsigned short* __restrict__ h2,
                                                float* __restrict__ as2,
                                                float* __restrict__ ad2, int N) {
    __shared__ unsigned short act_lds[16 * 264];
    const int tid = threadIdx.x;
    const int g = tid >> 5;            // group 0..7 (one node each)
    const int c = tid & 31;            // uint4 column: bf16 channels [8c, 8c+8)
    const long node = (long)blockIdx.x * 8 + g;
    const bool valid = node < N;
    {   // zero pad rows 8..15 (MFMA M=16, only 8 real rows)
        uint4 z; z.x = z.y = z.z = z.w = 0u;
        for (int i = tid; i < 264; i += 256) ((uint4*)(act_lds + 8 * 264))[i] = z;
    }
    const int hh = c >> 3;             // head 0..3
    const bool lo = hh < 2;
    const int sh = (hh & 1) << 4;
    const long beg = node * ELL_K;
    int dv = 0, siA = 0, siB = 0;
    unsigned pAx = 0, pAy = 0, pBx = 0, pBy = 0;
    if (valid) {
        dv = deg[node];
        siA = ell_src[beg + c];                 // edges 0..31 (lane c)
        siB = ell_src[beg + 32 + (c & 15)];     // edges 32..47
        const uint2 pAv = ell_pw[beg + c];
        const uint2 pBv = ell_pw[beg + 32 + (c & 15)];
        pAx = pAv.x; pAy = pAv.y; pBx = pBv.x; pBy = pBv.y;
    }
    const int cnt = valid ? (dv < ELL_K ? dv : ELL_K) : 0;
    float a0 = 0.f, a1 = 0.f, a2 = 0.f, a3 = 0.f;
    float a4 = 0.f, a5 = 0.f, a6 = 0.f, a7 = 0.f, s = 0.f;
#define EDGE8(v, p) { \
        a0 = fmaf(p, __uint_as_float((v).x << 16), a0); \
        a1 = fmaf(p, __uint_as_float((v).x & 0xffff0000u), a1); \
        a2 = fmaf(p, __uint_as_float((v).y << 16), a2); \
        a3 = fmaf(p, __uint_as_float((v).y & 0xffff0000u), a3); \
        a4 = fmaf(p, __uint_as_float((v).z << 16), a4); \
        a5 = fmaf(p, __uint_as_float((v).z & 0xffff0000u), a5); \
        a6 = fmaf(p, __uint_as_float((v).w << 16), a6); \
        a7 = fmaf(p, __uint_as_float((v).w & 0xffff0000u), a7); \
        s += p; }
#define DECL1(k) uint4 vv##k;
#define ISSUE1(k) if (j + k < cnt) { \
        const int e = j + k; \
        const int sv = __shfl((e < 32) ? siA : siB, e & 31, 32); \
        vv##k = hfeat[(long)sv * 32 + c]; }
#define CONS1(k) if (j + k < cnt) { \
        const int e = j + k; \
        const unsigned bx = (unsigned)__shfl((int)((e < 32) ? pAx : pBx), e & 31, 32); \
        const unsigned by = (unsigned)__shfl((int)((e < 32) ? pAy : pBy), e & 31, 32); \
        const unsigned pwu = lo ? bx : by; \
        const float p = h2f((unsigned short)((pwu >> sh) & 0xffffu)); \
        EDGE8(vv##k, p) }
    {   // main pass: edges 0..19 all in flight before first consume
        const int j = 0;
        B20(DECL1)
        B20(ISSUE1)
        B20(CONS1)
    }
    if (cnt > 20) {  // tail pass: edges 20..47 (~18% of nodes)
        const int j = 20;
        B20(DECL1)
        B20(ISSUE1)
        B20(CONS1)
        if (cnt > 40) {
            const int j2 = 40;
#define ISSUE1b(k) if (j2 + k < cnt) { \
            const int e = j2 + k; \
            const int sv = __shfl((e < 32) ? siA : siB, e & 31, 32); \
            vv##k = hfeat[(long)sv * 32 + c]; }
#define CONS1b(k) if (j2 + k < cnt) { \
            const int e = j2 + k; \
            const unsigned bx = (unsigned)__shfl((int)((e < 32) ? pAx : pBx), e & 31, 32); \
            const unsigned by = (unsigned)__shfl((int)((e < 32) ? pAy : pBy), e & 31, 32); \
            const unsigned pwu = lo ? bx : by; \
            const float p = h2f((unsigned short)((pwu >> sh) & 0xffffu)); \
            EDGE8(vv##k, p) }
            ISSUE1b(0) ISSUE1b(1) ISSUE1b(2) ISSUE1b(3)
            ISSUE1b(4) ISSUE1b(5) ISSUE1b(6) ISSUE1b(7)
            CONS1b(0) CONS1b(1) CONS1b(2) CONS1b(3)
            CONS1b(4) CONS1b(5) CONS1b(6) CONS1b(7)
#undef ISSUE1b
#undef CONS1b
        }
    }
#undef DECL1
#undef ISSUE1
#undef CONS1
#undef EDGE8
    const float4 b0 = ((const float4*)bias)[2 * c];
    const float4 b1 = ((const float4*)bias)[2 * c + 1];
    const float inv = (s > 0.f) ? 1.f / s : 0.f;
    uint4 o;
    o.x = (unsigned)f2bf(fmaxf(fmaf(a0, inv, b0.x), 0.f)) |
          ((unsigned)f2bf(fmaxf(fmaf(a1, inv, b0.y), 0.f)) << 16);
    o.y = (unsigned)f2bf(fmaxf(fmaf(a2, inv, b0.z), 0.f)) |
          ((unsigned)f2bf(fmaxf(fmaf(a3, inv, b0.w), 0.f)) << 16);
    o.z = (unsigned)f2bf(fmaxf(fmaf(a4, inv, b1.x), 0.f)) |
          ((unsigned)f2bf(fmaxf(fmaf(a5, inv, b1.y), 0.f)) << 16);
    o.w = (unsigned)f2bf(fmaxf(fmaf(a6, inv, b1.z), 0.f)) |
          ((unsigned)f2bf(fmaxf(fmaf(a7, inv, b1.w), 0.f)) << 16);
    *(uint4*)&act_lds[g * 264 + c * 8] = o;    // act1 row g, bf16 cols [8c,8c+8)
    __syncthreads();
    // ---- Phase B: wave 0 does the 16x64 GEMM2 tile (rows 8..15 are zeros)
    if (tid < 64) {
        const int l16 = tid & 15, quad = tid >> 4;
        bf16x8_t af[8];
#pragma unroll
        for (int ks = 0; ks < 8; ks++)
            af[ks] = *(const bf16x8_t*)&act_lds[l16 * 264 + ks * 32 + quad * 8];
        float psA[4] = {0.f, 0.f, 0.f, 0.f}, pdA[4] = {0.f, 0.f, 0.f, 0.f};
#pragma unroll
        for (int t = 0; t < 4; t++) {
            f32x4_t acc = {0.f, 0.f, 0.f, 0.f};
#pragma unroll
            for (int ks = 0; ks < 8; ks++) {
                bf16x8_t bf = *(const bf16x8_t*)(Wt2 + (size_t)(t * 16 + l16) * 256 + ks * 32 + quad * 8);
                acc = __builtin_amdgcn_mfma_f32_16x16x32_bf16(af[ks], bf, acc, 0, 0, 0);
            }
            const float aswv = asw2[t * 16 + l16];
            const float adwv = adw2[t * 16 + l16];
#pragma unroll
            for (int r = 0; r < 4; r++) {
                const int row8 = quad * 4 + r;
                const long gn = (long)blockIdx.x * 8 + row8;
                if (row8 < 8 && gn < N) h2[gn * 64 + t * 16 + l16] = f2bf(acc[r]);
                psA[r] = fmaf(acc[r], aswv, psA[r]);
                pdA[r] = fmaf(acc[r], adwv, pdA[r]);
            }
        }
#pragma unroll
        for (int r = 0; r < 4; r++) {
            float ps = psA[r], pd = pdA[r];
#pragma unroll
            for (int o2 = 8; o2 > 0; o2 >>= 1) {
                ps += __shfl_down(ps, o2, 16);
                pd += __shfl_down(pd, o2, 16);
            }
            const int row8 = quad * 4 + r;
            const long gn = (long)blockIdx.x * 8 + row8;
            if (l16 == 0 && row8 < 8 && gn < N) { as2[gn] = ps; ad2[gn] = pd; }
        }
    }
}

// ---------------- layer-2 aggregate (H=1): one node per 16-lane group, uint2/lane.
// Lane-parallel si/alpha preload (clamped before indexing as_), intra-16 shfl
// broadcast, 20-slot issue window + guarded tail. (R5 form, unchanged)
__global__ __launch_bounds__(256) void agg2_k(const unsigned short* __restrict__ hfeat,
                                              const float* __restrict__ as_,
                                              const float* __restrict__ ad_,
                                              const int* __restrict__ deg,
                                              const int* __restrict__ ell_src,
                                              const float* __restrict__ bias,
                                              unsigned short* __restrict__ outb,
                                              float* __restrict__ outf,
                                              const int* __restrict__ flags, int N) {
    const int tid = threadIdx.x;
    const int g = tid >> 4;            // group 0..15 (one node each)
    const int c = tid & 15;            // uint2 column: bf16 channels [4c, 4c+4)
    const long node = (long)blockIdx.x * 16 + g;
    if (node >= N) return;
    const long beg = node * ELL_K;
    const int dv = deg[node];
    const int rA = ell_src[beg + c];           // edges 0..15
    const int rB = ell_src[beg + 16 + c];      // edges 16..31
    const int rC = ell_src[beg + 32 + c];      // edges 32..47
    const float adn = ad_[node];
    const int cnt = dv < ELL_K ? dv : ELL_K;
    // clamp garbage slots (uninitialized ell rows) before indexing as_
    const int sA = (c      < cnt) ? rA : 0;
    const int sB = (c + 16 < cnt) ? rB : 0;
    const int sC = (c + 32 < cnt) ? rC : 0;
    const float avA = as_[sA];
    const float avB = as_[sB];
    const float avC = as_[sC];
    const uint2* hv = (const uint2*)hfeat;
    float sm = 0.f, a0 = 0.f, a1 = 0.f, a2 = 0.f, a3 = 0.f;
#define EDGE4(v, p) { \
        a0 = fmaf(p, __uint_as_float((v).x << 16), a0); \
        a1 = fmaf(p, __uint_as_float((v).x & 0xffff0000u), a1); \
        a2 = fmaf(p, __uint_as_float((v).y << 16), a2); \
        a3 = fmaf(p, __uint_as_float((v).y & 0xffff0000u), a3); \
        sm += p; }
#define DECL2(k) uint2 vv##k;
#define ISSUE2(k) if (j + k < cnt) { \
        const int e = j + k; \
        const int sv = __shfl((e < 16) ? sA : ((e < 32) ? sB : sC), e & 15, 16); \
        vv##k = hv[(long)sv * 16 + c]; }
#define CONS2(k) if (j + k < cnt) { \
        const int e = j + k; \
        const float av = __shfl((e < 16) ? avA : ((e < 32) ? avB : avC), e & 15, 16); \
        float t = av + adn; t = t > 0.f ? t : LRELU_SLOPE * t; \
        const float p = __expf(t); \
        EDGE4(vv##k, p) }
    {   // main pass: edges 0..19
        const int j = 0;
        B20(DECL2)
        B20(ISSUE2)
        B20(CONS2)
    }
    if (cnt > 20) {  // tail: edges 20..47
        const int j = 20;
        B20(DECL2)
        B20(ISSUE2)
        B20(CONS2)
        if (cnt > 40) {
            const int j2 = 40;
#define ISSUE2b(k) if (j2 + k < cnt) { \
            const int e = j2 + k; \
            const int sv = __shfl((e < 16) ? sA : ((e < 32) ? sB : sC), e & 15, 16); \
            vv##k = hv[(long)sv * 16 + c]; }
#define CONS2b(k) if (j2 + k < cnt) { \
            const int e = j2 + k; \
            const float av = __shfl((e < 16) ? avA : ((e < 32) ? avB : avC), e & 15, 16); \
            float t = av + adn; t = t > 0.f ? t : LRELU_SLOPE * t; \
            const float p = __expf(t); \
            EDGE4(vv##k, p) }
            ISSUE2b(0) ISSUE2b(1) ISSUE2b(2) ISSUE2b(3)
            ISSUE2b(4) ISSUE2b(5) ISSUE2b(6) ISSUE2b(7)
            CONS2b(0) CONS2b(1) CONS2b(2) CONS2b(3)
            CONS2b(4) CONS2b(5) CONS2b(6) CONS2b(7)
#undef ISSUE2b
#undef CONS2b
        }
    }
#undef DECL2
#undef ISSUE2
#undef CONS2
#undef EDGE4
    const float inv = 1.f / sm;
    const float4 bi = ((const float4*)bias)[c];
    const float v0 = fmaf(a0, inv, bi.x);
    const float v1 = fmaf(a1, inv, bi.y);
    const float v2 = fmaf(a2, inv, bi.z);
    const float v3 = fmaf(a3, inv, bi.w);
    if (flags[1] != 0) {
        uint2 o;
        o.x = (unsigned)f2bf(v0) | ((unsigned)f2bf(v1) << 16);
        o.y = (unsigned)f2bf(v2) | ((unsigned)f2bf(v3) << 16);
        ((uint2*)outb)[node * 16 + c] = o;
    } else {
        float4 o; o.x = v0; o.y = v1; o.z = v2; o.w = v3;
        ((float4*)outf)[node * 16 + c] = o;
    }
}

static inline size_t alignup(size_t v, size_t a) { return (v + a - 1) & ~(a - 1); }

extern "C" void kernel_launch(void* const* d_in, const int* in_sizes, int n_in,
                              void* d_out, int out_size, void* d_ws, size_t ws_size,
                              hipStream_t stream) {
    const void* x  = d_in[0];
    const int*  ei = (const int*)d_in[1];

    const int N = in_sizes[0] / 128;   // 50000
    const int E = in_sizes[1] / 2;     // 800000
    const int T = E + N;

    size_t off = 0;
    char* w = (char*)d_ws;
    auto take = [&](size_t bytes) { void* p = w + off; off = alignup(off + bytes, 256); return p; };

    int*   flags = (int*)take(256);
    unsigned short* Wt1 = (unsigned short*)take((size_t)256 * 128 * 2);
    unsigned short* Wt2 = (unsigned short*)take((size_t)64 * 256 * 2);
    float* as1w = (float*)take(256 * 4);
    float* ad1w = (float*)take(256 * 4);
    float* b1f  = (float*)take(256 * 4);
    float* as2w = (float*)take(64 * 4);
    float* ad2w = (float*)take(64 * 4);
    float* b2f  = (float*)take(64 * 4);
    unsigned short* h1b = (unsigned short*)take((size_t)N * 256 * 2);
    unsigned short* h2b = (unsigned short*)take((size_t)N * 64 * 2);   // fused agg1+gemm2 output
    float* as1 = (float*)take((size_t)N * 4 * 4);
    float* ad1 = (float*)take((size_t)N * 4 * 4);
    float* as2 = (float*)take((size_t)N * 4);
    float* ad2 = (float*)take((size_t)N * 4);
    int* deg   = (int*)take((size_t)N * 4);
    int* ell_src = (int*)take((size_t)N * ELL_K * 4);
    uint2* ell_pw = (uint2*)take((size_t)N * ELL_K * 8);

    PrepDesc pd;
    pd.ssrc[0] = d_in[3]; pd.sdst[0] = as1w; pd.slen[0] = 256;
    pd.ssrc[1] = d_in[4]; pd.sdst[1] = ad1w; pd.slen[1] = 256;
    pd.ssrc[2] = d_in[5]; pd.sdst[2] = b1f;  pd.slen[2] = 256;
    pd.ssrc[3] = d_in[7]; pd.sdst[3] = as2w; pd.slen[3] = 64;
    pd.ssrc[4] = d_in[8]; pd.sdst[4] = ad2w; pd.slen[4] = 64;
    pd.ssrc[5] = d_in[9]; pd.sdst[5] = b2f;  pd.slen[5] = 64;
    prep_k<<<64, 256, 0, stream>>>((const unsigned short*)x, ei, d_in[2], d_in[6],
                                   Wt1, Wt2, pd, flags, deg, N);

    gemm1_k<<<(N + 63) / 64, 256, 0, stream>>>(x, Wt1, as1w, ad1w, h1b, as1, ad1, N, flags);
    ell_k<<<(T + 255) / 256, 256, 0, stream>>>(ei, E, N, flags, deg, ell_src, ell_pw, as1, ad1);
    agg1g2_k<<<(N + 7) / 8, 256, 0, stream>>>((const uint4*)h1b, deg, ell_src, ell_pw, b1f,
                                              Wt2, as2w, ad2w, h2b, as2, ad2, N);
    agg2_k<<<(N + 15) / 16, 256, 0, stream>>>(h2b, as2, ad2, deg, ell_src, b2f,
                                              (unsigned short*)d_out, (float*)d_out, flags, N);
}